// Round 15
// baseline (135.057 us; speedup 1.0000x reference)
//
#include <hip/hip_runtime.h>
#include <hip/hip_bf16.h>

// Q3 unpack: each int32 holds 10 x 3-bit fields at shifts 27,24,...,0.
// Output block k (k=0..9) along dim 0 is ((packed >> (27-3k)) & 7), int32.
//
// CU-pure phased streaming (one 1024-thread block per CU, 16 waves
// phase-locked, one pure write stream per CU per phase) + READ HIDING:
// each block handles 2 chunks (128 KB each). Chunk B's loads are issued
// during chunk A's phase-0 writes (1R+1W copy regime, known 6.3 TB/s), so
// only chunk A's read (~5 us GPU-wide) remains serial. Full-drain
// __syncthreads() boundaries (R13 vs R14 showed counted ~= full in the
// CU-pure regime; the first A-boundary also conveniently drains B's loads).

typedef int v4i __attribute__((ext_vector_type(4)));

constexpr int TPB = 1024;
constexpr int VPT = 8;                 // v4i per thread per chunk
constexpr int CVB = TPB * VPT;         // 8192 v4i = 128 KB per chunk
constexpr int CPB = 2;                 // chunks per block

__global__ __launch_bounds__(1024) void q3_unpack_kernel(
    const v4i* __restrict__ in, v4i* __restrict__ out, int stride_vec) {
    const int lane = threadIdx.x & 63;
    const int w = threadIdx.x >> 6;    // 16 waves
    const size_t base = (size_t)blockIdx.x * (CPB * CVB);
    // wave-contiguous within each chunk
    const size_t wA = base + (size_t)w * (64 * VPT) + lane;
    const size_t wB = wA + CVB;

    v4i pA[VPT], pB[VPT];
#pragma unroll
    for (int j = 0; j < VPT; ++j)
        pA[j] = __builtin_nontemporal_load(&in[wA + (size_t)j * 64]);

    __syncthreads();   // A loaded + all 16 waves aligned

    // ---- chunk A phases; B's loads issued under phase 0 ----
#pragma unroll
    for (int k = 0; k < 10; ++k) {
        const int sh = 27 - 3 * k;
        const size_t ob = (size_t)k * (size_t)stride_vec + wA;
#pragma unroll
        for (int j = 0; j < VPT; ++j) {
            v4i v = (pA[j] >> sh) & 7;
            __builtin_nontemporal_store(v, &out[ob + (size_t)j * 64]);
        }
        if (k == 0) {
            // hide chunk B's read under A's write phases
#pragma unroll
            for (int j = 0; j < VPT; ++j)
                pB[j] = __builtin_nontemporal_load(&in[wB + (size_t)j * 64]);
        }
        __syncthreads();   // full drain: pure stream per phase
    }

    // ---- chunk B phases (loads long since drained) ----
#pragma unroll
    for (int k = 0; k < 10; ++k) {
        const int sh = 27 - 3 * k;
        const size_t ob = (size_t)k * (size_t)stride_vec + wB;
#pragma unroll
        for (int j = 0; j < VPT; ++j) {
            v4i v = (pB[j] >> sh) & 7;
            __builtin_nontemporal_store(v, &out[ob + (size_t)j * 64]);
        }
        if (k < 9) __syncthreads();
    }
}

extern "C" void kernel_launch(void* const* d_in, const int* in_sizes, int n_in,
                              void* d_out, int out_size, void* d_ws, size_t ws_size,
                              hipStream_t stream) {
    const int* packed = (const int*)d_in[0];
    int* out = (int*)d_out;

    const int n_words = in_sizes[0];     // 4096*4096 = 16,777,216
    const int nvec = n_words / 4;        // 4,194,304 v4i
    const int stride_vec = n_words / 4;  // k-block stride in v4i units

    const int blocks = nvec / (CPB * CVB);   // 256 blocks = 1 per CU

    q3_unpack_kernel<<<blocks, TPB, 0, stream>>>(
        (const v4i*)packed, (v4i*)out, stride_vec);
}

// Round 16
// 120.837 us; speedup vs baseline: 1.1177x; 1.1177x over previous
//
#include <hip/hip_runtime.h>
#include <hip/hip_bf16.h>

// Q3 unpack: each int32 holds 10 x 3-bit fields at shifts 27,24,...,0.
// Output block k (k=0..9) along dim 0 is ((packed >> (27-3k)) & 7), int32.
//
// BEST VARIANT (R14 revert): CU-pure phased streaming. One 1024-thread
// block per CU (256 blocks, 16 waves phase-locked), each phase writes ONE
// pure 64 MB output stream per CU (stream purity at wave/block/CU level was
// the governing variable: 153->138->121 us as each mixing level was
// removed). Counted boundary drain (vmcnt(4) + raw s_barrier) keeps the
// store pipe warm; R15 proved splitting phases to hide the read regresses
// (boundary count doubles). 738 MB fabric bytes / 120.7 us = 6.11 TB/s =
// 97% of the D2D-copy ceiling (6.3 TB/s).

typedef int v4i __attribute__((ext_vector_type(4)));

constexpr int TPB = 1024;
constexpr int VPT = 16;                // v4i per thread
constexpr int VPB = TPB * VPT;         // 16384 v4i = 256 KB per block

__global__ __launch_bounds__(1024) void q3_unpack_kernel(
    const v4i* __restrict__ in, v4i* __restrict__ out, int stride_vec) {
    const int lane = threadIdx.x & 63;
    const int w = threadIdx.x >> 6;    // 16 waves
    const size_t wbase = (size_t)blockIdx.x * VPB + (size_t)w * (64 * VPT) + lane;

    v4i p[VPT];
#pragma unroll
    for (int j = 0; j < VPT; ++j)
        p[j] = __builtin_nontemporal_load(&in[wbase + (size_t)j * 64]);

    __syncthreads();   // loads complete + all 16 waves aligned

#pragma unroll
    for (int k = 0; k < 10; ++k) {
        const int sh = 27 - 3 * k;
        const size_t ob = (size_t)k * (size_t)stride_vec + wbase;
#pragma unroll
        for (int j = 0; j < VPT; ++j) {
            v4i v = (p[j] >> sh) & 7;
            __builtin_nontemporal_store(v, &out[ob + (size_t)j * 64]);
        }
        if (k < 9) {
            // Counted drain: keep 4 tail stores in flight across the
            // boundary; raw barrier (no implicit vmcnt(0)) re-aligns waves.
            asm volatile("s_waitcnt vmcnt(4)" ::: "memory");
            __builtin_amdgcn_s_barrier();
        }
    }
}

extern "C" void kernel_launch(void* const* d_in, const int* in_sizes, int n_in,
                              void* d_out, int out_size, void* d_ws, size_t ws_size,
                              hipStream_t stream) {
    const int* packed = (const int*)d_in[0];
    int* out = (int*)d_out;

    const int n_words = in_sizes[0];     // 4096*4096 = 16,777,216
    const int nvec = n_words / 4;        // 4,194,304 v4i
    const int stride_vec = n_words / 4;  // k-block stride in v4i units

    const int blocks = nvec / VPB;       // 256 blocks = 1 per CU

    q3_unpack_kernel<<<blocks, TPB, 0, stream>>>(
        (const v4i*)packed, (v4i*)out, stride_vec);
}